// Round 2
// baseline (261.821 us; speedup 1.0000x reference)
//
#include <hip/hip_runtime.h>

// MNIST_RNN R11: instruction-count reduction. R9->R10 post-mortem: wall
// tracks ISSUED INSTRUCTIONS (VALU-cycles invariant 4916->5103 while
// serial-segment count halved and wall moved only -4%) -> SIMD issue-
// bound at 2 waves/SIMD, not latency-chain-bound. This round cuts issue
// count at constant structure:
//  1) v_cvt_pk_bf16_f32 packing: hi/lo split = 4 VALU/elem (was ~12).
//  2) K-reorder: zoneA = interleaved (hi,lo) pairs x w_hi, zoneB =
//     hi x w_lo. Same 3 product terms, same K (114/60), same MFMA count,
//     but each h/x element = 1 ds_write_b32 + 1 ds_write_b16 (was 3 b16).
//     DS instrs/iter 77 -> 58.
//  3) Sigmoid-only tiles T0/T2 use 4-op rcp(1+exp(-v)) (T1 mixed stays
//     runtime-a). 4) One fewer FENCE region.
// Numerics: same RNE split, same products; only K-accumulation order
// inside MFMA changes (lsb-level).

#define HDIM 10
#define DDIM 28
#define TSTEPS 28

typedef __attribute__((ext_vector_type(8))) short short8;
typedef __attribute__((ext_vector_type(4))) float f32x4;

__device__ __forceinline__ unsigned short bf16_rne(float f) {
    unsigned u = __builtin_bit_cast(unsigned, f);
    u += 0x7FFFu + ((u >> 16) & 1u);
    return (unsigned short)(u >> 16);
}
__device__ __forceinline__ float bf16_f(unsigned short h) {
    unsigned u = ((unsigned)h) << 16;
    return __builtin_bit_cast(float, u);
}
// packed {lo:hi} bf16 split of v: low16 = bf16_rne(v), high16 = bf16_rne(v - hi)
__device__ __forceinline__ unsigned pk_hl(float v) {
    unsigned a, p;
    const float z = 0.0f;
    asm("v_cvt_pk_bf16_f32 %0, %1, %2" : "=v"(a) : "v"(v), "v"(z));
    const float hif = __builtin_bit_cast(float, a << 16);
    const float d = v - hif;
    asm("v_cvt_pk_bf16_f32 %0, %1, %2" : "=v"(p) : "v"(v), "v"(d));
    return p;
}
__device__ __forceinline__ float sig_f(float v) {
    return __builtin_amdgcn_rcpf(1.0f + __expf(-v));
}
// a=1: sigmoid; a=2: tanh
__device__ __forceinline__ float act_eval(float v, float a) {
    return a * __builtin_amdgcn_rcpf(1.0f + __expf(-a * v)) + (1.0f - a);
}
__device__ __forceinline__ float tanh_f(float v) {
    return 2.0f * __builtin_amdgcn_rcpf(1.0f + __expf(-2.0f * v)) - 1.0f;
}

#define FENCE() __asm volatile("" ::: "memory")
#define WR32(arrp, sidx, val) (*(unsigned*)&(arrp)[(sidx)] = (val))

__global__ __launch_bounds__(64) void lstm2_mfma_kernel(
    const float* __restrict__ x,
    const float* __restrict__ w_ih0, const float* __restrict__ w_hh0,
    const float* __restrict__ b_ih0, const float* __restrict__ b_hh0,
    const float* __restrict__ w_ih1, const float* __restrict__ w_hh1,
    const float* __restrict__ b_ih1, const float* __restrict__ b_hh1,
    const float* __restrict__ w_cls, const float* __restrict__ b_cls,
    float* __restrict__ out)
{
    // A0 row (stride 136 shorts): [ (x_d hi,lo) pairs d<28 : cols 0..55 |
    //   (h0_u hi,lo) pairs u<10 : 56..75 | x_d hi : 76..103 |
    //   h0_u hi : 104..113 | pad 114..135 ]
    // A1 row (stride 72): [ (h0 hi,lo) 0..19 | (h1 hi,lo) 20..39 |
    //   h0 hi 40..49 | h1 hi 50..59 | pad 60..71 ]
    __shared__ unsigned short uA0[16 * 136];
    __shared__ unsigned short uA1[16 * 72];
    __shared__ float gb[2][48 * 20];   // [0]=L0 gates (C), [1]=L1 gates (D)
    __shared__ float hfin[16 * 12];

    const int l  = threadIdx.x;
    const int lm = l & 15;
    const int q  = l >> 4;
    const int sbase = blockIdx.x * 16;

    // ---- zero A-panel pads (NaN*0=NaN in MFMA) ----
    for (int i = l; i < 16 * 22; i += 64) uA0[(i / 22) * 136 + 114 + (i % 22)] = 0;
    for (int i = l; i < 16 * 12; i += 64) uA1[(i / 12) * 72 + 60 + (i % 12)] = 0;

    // ---- build B-fragments in registers (once) ----
    // B0: kk<76: pair zone -> w_hi (j2=kk>>1); kk in [76,114): w_lo (d=kk-76)
    // B1: kk<40: pair zone -> w_hi; kk in [40,60): w_lo
    short8 B0[3][4], B1[3][2];
    #pragma unroll
    for (int T = 0; T < 3; ++T) {
        const int n = lm + 16 * T;
        #pragma unroll
        for (int c = 0; c < 4; ++c) {
            #pragma unroll
            for (int j = 0; j < 8; ++j) {
                const int kk = 32 * c + 8 * q + j;
                unsigned short bits = 0;
                if (n < 40 && kk < 114) {
                    if (kk < 76) {
                        const int j2 = kk >> 1;
                        const float w = (j2 < 28) ? w_ih0[n * 28 + j2]
                                                  : w_hh0[n * 10 + (j2 - 28)];
                        bits = bf16_rne(w);
                    } else {
                        const int d = kk - 76;
                        const float w = (d < 28) ? w_ih0[n * 28 + d]
                                                 : w_hh0[n * 10 + (d - 28)];
                        const unsigned short hi = bf16_rne(w);
                        bits = bf16_rne(w - bf16_f(hi));
                    }
                }
                B0[T][c][j] = (short)bits;
            }
        }
        #pragma unroll
        for (int c = 0; c < 2; ++c) {
            #pragma unroll
            for (int j = 0; j < 8; ++j) {
                const int kk = 32 * c + 8 * q + j;
                unsigned short bits = 0;
                if (n < 40 && kk < 60) {
                    if (kk < 40) {
                        const int j2 = kk >> 1;
                        const float w = (j2 < 10) ? w_ih1[n * 10 + j2]
                                                  : w_hh1[n * 10 + (j2 - 10)];
                        bits = bf16_rne(w);
                    } else {
                        const int d = kk - 40;
                        const float w = (d < 10) ? w_ih1[n * 10 + d]
                                                 : w_hh1[n * 10 + (d - 10)];
                        const unsigned short hi = bf16_rne(w);
                        bits = bf16_rne(w - bf16_f(hi));
                    }
                }
                B1[T][c][j] = (short)bits;
            }
        }
    }

    // biases (folded into MFMA C-init); T1 per-lane activation selector
    float bias0[3], bias1[3];
    #pragma unroll
    for (int T = 0; T < 3; ++T) {
        const int n = lm + 16 * T;
        bias0[T] = (n < 40) ? (b_ih0[n] + b_hh0[n]) : 0.0f;
        bias1[T] = (n < 40) ? (b_ih1[n] + b_hh1[n]) : 0.0f;
    }
    const float a1v = (lm >= 4 && lm < 14) ? 2.0f : 1.0f;  // T1: g rows -> tanh

    // ---- x pipeline: lane owns 7 of the 448 (sample,d) elements ----
    int xoff[7], lofsA[7], lofsB[7]; float xn[7];
    #pragma unroll
    for (int i = 0; i < 7; ++i) {
        const int f = l + 64 * i;
        const int sm = f / 28, d = f - 28 * sm;
        lofsA[i] = sm * 136 + 2 * d;        // b32 (pair zone)
        lofsB[i] = sm * 136 + 76 + d;       // b16 (hi zone)
        xoff[i] = (sbase + sm) * (TSTEPS * DDIM) + d;
        xn[i] = x[xoff[i]];                 // t = 0
    }
    #pragma unroll
    for (int i = 0; i < 7; ++i) {
        const unsigned p = pk_hl(xn[i]);
        WR32(uA0, lofsA[i], p);
        uA0[lofsB[i]] = (unsigned short)p;
    }
    // zero h zones (h0 = h1 = 0 at t=0)
    if (lm < 10) {
        #pragma unroll
        for (int r = 0; r < 4; ++r) {
            const int m = 4 * q + r;
            unsigned short* r0 = &uA0[m * 136];
            WR32(r0, 56 + 2 * lm, 0u); r0[104 + lm] = 0;
            unsigned short* r1 = &uA1[m * 72];
            WR32(r1, 2 * lm, 0u);      r1[40 + lm] = 0;   // h0
            WR32(r1, 20 + 2 * lm, 0u); r1[50 + lm] = 0;   // h1
        }
    }
    FENCE();

    float c0s[4] = {0, 0, 0, 0}, c1s[4] = {0, 0, 0, 0};
    float h1v[4] = {0, 0, 0, 0};
    float h0v[4];
    short8 A0f[4], A1f[2];
    float* const gb0 = gb[0];
    float* const gb1 = gb[1];

    // ================= prologue: cell0(0) =================
    #pragma unroll
    for (int c = 0; c < 4; ++c)
        A0f[c] = *(const short8*)&uA0[lm * 136 + 32 * c + 8 * q];
    FENCE();
    #pragma unroll
    for (int i = 0; i < 7; ++i) { xoff[i] += DDIM; xn[i] = x[xoff[i]]; }  // x(1)
    {
        f32x4 C[3];
        #pragma unroll
        for (int T = 0; T < 3; ++T) {
            f32x4 acc = {bias0[T], bias0[T], bias0[T], bias0[T]};
            #pragma unroll
            for (int c = 0; c < 4; ++c)
                acc = __builtin_amdgcn_mfma_f32_16x16x32_bf16(A0f[c], B0[T][c], acc, 0, 0, 0);
            C[T] = acc;
        }
        f32x4 g0, g1t, g2;
        #pragma unroll
        for (int r = 0; r < 4; ++r) {
            g0[r]  = sig_f(C[0][r]);
            g1t[r] = act_eval(C[1][r], a1v);
            g2[r]  = sig_f(C[2][r]);
        }
        *(f32x4*)&gb0[(lm     ) * 20 + 4 * q] = g0;
        *(f32x4*)&gb0[(lm + 16) * 20 + 4 * q] = g1t;
        *(f32x4*)&gb0[(lm + 32) * 20 + 4 * q] = g2;
    }
    FENCE();
    {
        const f32x4 iv = *(const f32x4*)&gb0[(lm     ) * 20 + 4 * q];
        const f32x4 fv = *(const f32x4*)&gb0[(lm + 10) * 20 + 4 * q];
        const f32x4 gg = *(const f32x4*)&gb0[(lm + 20) * 20 + 4 * q];
        const f32x4 ov = *(const f32x4*)&gb0[(lm + 30) * 20 + 4 * q];
        #pragma unroll
        for (int r = 0; r < 4; ++r) {
            const float c = fv[r] * c0s[r] + iv[r] * gg[r];
            c0s[r] = c;
            h0v[r] = ov[r] * tanh_f(c);
        }
        if (lm < 10) {
            #pragma unroll
            for (int r = 0; r < 4; ++r) {
                const int m = 4 * q + r;
                const unsigned p0 = pk_hl(h0v[r]);
                unsigned short* r0 = &uA0[m * 136];
                WR32(r0, 56 + 2 * lm, p0); r0[104 + lm] = (unsigned short)p0;
                unsigned short* r1 = &uA1[m * 72];
                WR32(r1, 2 * lm, p0);      r1[40 + lm] = (unsigned short)p0;
            }
        }
        // write x(1)
        #pragma unroll
        for (int i = 0; i < 7; ++i) {
            const unsigned p = pk_hl(xn[i]);
            WR32(uA0, lofsA[i], p);
            uA0[lofsB[i]] = (unsigned short)p;
        }
    }
    FENCE();

    // ===== main loop: iteration t computes cell1(t) AND cell0(t+1) =====
    #pragma unroll 1
    for (int t = 0; t < TSTEPS - 1; ++t) {
        // ---- read phase: A1 = {h0(t), h1(t-1)}, A0 = {x(t+1), h0(t)} ----
        #pragma unroll
        for (int c = 0; c < 2; ++c)
            A1f[c] = *(const short8*)&uA1[lm * 72 + 32 * c + 8 * q];
        #pragma unroll
        for (int c = 0; c < 4; ++c)
            A0f[c] = *(const short8*)&uA0[lm * 136 + 32 * c + 8 * q];
        FENCE();

        // prefetch x(t+2)
        if (t < TSTEPS - 2) {
            #pragma unroll
            for (int i = 0; i < 7; ++i) { xoff[i] += DDIM; xn[i] = x[xoff[i]]; }
        }

        // ---- MFMA phase: 6 independent accumulator chains ----
        f32x4 C[3], D[3];
        #pragma unroll
        for (int T = 0; T < 3; ++T) {
            f32x4 accD = {bias1[T], bias1[T], bias1[T], bias1[T]};
            #pragma unroll
            for (int c = 0; c < 2; ++c)
                accD = __builtin_amdgcn_mfma_f32_16x16x32_bf16(A1f[c], B1[T][c], accD, 0, 0, 0);
            D[T] = accD;
            f32x4 accC = {bias0[T], bias0[T], bias0[T], bias0[T]};
            #pragma unroll
            for (int c = 0; c < 4; ++c)
                accC = __builtin_amdgcn_mfma_f32_16x16x32_bf16(A0f[c], B0[T][c], accC, 0, 0, 0);
            C[T] = accC;
        }

        // ---- act phase: T0/T2 pure sigmoid, T1 mixed ----
        {
            f32x4 d0, d1, d2, e0, e1, e2;
            #pragma unroll
            for (int r = 0; r < 4; ++r) {
                d0[r] = sig_f(D[0][r]);
                d1[r] = act_eval(D[1][r], a1v);
                d2[r] = sig_f(D[2][r]);
                e0[r] = sig_f(C[0][r]);
                e1[r] = act_eval(C[1][r], a1v);
                e2[r] = sig_f(C[2][r]);
            }
            *(f32x4*)&gb1[(lm     ) * 20 + 4 * q] = d0;
            *(f32x4*)&gb1[(lm + 16) * 20 + 4 * q] = d1;
            *(f32x4*)&gb1[(lm + 32) * 20 + 4 * q] = d2;
            *(f32x4*)&gb0[(lm     ) * 20 + 4 * q] = e0;
            *(f32x4*)&gb0[(lm + 16) * 20 + 4 * q] = e1;
            *(f32x4*)&gb0[(lm + 32) * 20 + 4 * q] = e2;
        }
        FENCE();

        // ---- update + write phase ----
        {
            const f32x4 iv1 = *(const f32x4*)&gb1[(lm     ) * 20 + 4 * q];
            const f32x4 fv1 = *(const f32x4*)&gb1[(lm + 10) * 20 + 4 * q];
            const f32x4 gg1 = *(const f32x4*)&gb1[(lm + 20) * 20 + 4 * q];
            const f32x4 ov1 = *(const f32x4*)&gb1[(lm + 30) * 20 + 4 * q];
            const f32x4 iv0 = *(const f32x4*)&gb0[(lm     ) * 20 + 4 * q];
            const f32x4 fv0 = *(const f32x4*)&gb0[(lm + 10) * 20 + 4 * q];
            const f32x4 gg0 = *(const f32x4*)&gb0[(lm + 20) * 20 + 4 * q];
            const f32x4 ov0 = *(const f32x4*)&gb0[(lm + 30) * 20 + 4 * q];
            #pragma unroll
            for (int r = 0; r < 4; ++r) {
                const float c1 = fv1[r] * c1s[r] + iv1[r] * gg1[r];
                c1s[r] = c1;
                h1v[r] = ov1[r] * tanh_f(c1);
                const float c0 = fv0[r] * c0s[r] + iv0[r] * gg0[r];
                c0s[r] = c0;
                h0v[r] = ov0[r] * tanh_f(c0);
            }
            if (lm < 10) {
                #pragma unroll
                for (int r = 0; r < 4; ++r) {
                    const int m = 4 * q + r;
                    const unsigned p1 = pk_hl(h1v[r]);
                    unsigned short* r1 = &uA1[m * 72];
                    WR32(r1, 20 + 2 * lm, p1); r1[50 + lm] = (unsigned short)p1;
                    const unsigned p0 = pk_hl(h0v[r]);
                    WR32(r1, 2 * lm, p0);      r1[40 + lm] = (unsigned short)p0;
                    unsigned short* r0 = &uA0[m * 136];
                    WR32(r0, 56 + 2 * lm, p0); r0[104 + lm] = (unsigned short)p0;
                }
            }
            // write x(t+2) (A0 reads for t+1 already done this iter)
            if (t < TSTEPS - 2) {
                #pragma unroll
                for (int i = 0; i < 7; ++i) {
                    const unsigned p = pk_hl(xn[i]);
                    WR32(uA0, lofsA[i], p);
                    uA0[lofsB[i]] = (unsigned short)p;
                }
            }
        }
        FENCE();
    }

    // ================= epilogue: cell1(27) =================
    {
        #pragma unroll
        for (int c = 0; c < 2; ++c)
            A1f[c] = *(const short8*)&uA1[lm * 72 + 32 * c + 8 * q];
        FENCE();
        f32x4 D[3];
        #pragma unroll
        for (int T = 0; T < 3; ++T) {
            f32x4 acc = {bias1[T], bias1[T], bias1[T], bias1[T]};
            #pragma unroll
            for (int c = 0; c < 2; ++c)
                acc = __builtin_amdgcn_mfma_f32_16x16x32_bf16(A1f[c], B1[T][c], acc, 0, 0, 0);
            D[T] = acc;
        }
        f32x4 d0, d1, d2;
        #pragma unroll
        for (int r = 0; r < 4; ++r) {
            d0[r] = sig_f(D[0][r]);
            d1[r] = act_eval(D[1][r], a1v);
            d2[r] = sig_f(D[2][r]);
        }
        *(f32x4*)&gb1[(lm     ) * 20 + 4 * q] = d0;
        *(f32x4*)&gb1[(lm + 16) * 20 + 4 * q] = d1;
        *(f32x4*)&gb1[(lm + 32) * 20 + 4 * q] = d2;
        FENCE();
        const f32x4 iv = *(const f32x4*)&gb1[(lm     ) * 20 + 4 * q];
        const f32x4 fv = *(const f32x4*)&gb1[(lm + 10) * 20 + 4 * q];
        const f32x4 gg = *(const f32x4*)&gb1[(lm + 20) * 20 + 4 * q];
        const f32x4 ov = *(const f32x4*)&gb1[(lm + 30) * 20 + 4 * q];
        #pragma unroll
        for (int r = 0; r < 4; ++r) {
            const float c = fv[r] * c1s[r] + iv[r] * gg[r];
            h1v[r] = ov[r] * tanh_f(c);
        }
    }

    // ---- classifier ----
    if (lm < 10) {
        #pragma unroll
        for (int r = 0; r < 4; ++r) hfin[(4 * q + r) * 12 + lm] = h1v[r];
    }
    FENCE();
    if (lm < 10) {
        float wc[10];
        #pragma unroll
        for (int j = 0; j < 10; ++j) wc[j] = w_cls[lm * 10 + j];
        const float bo = b_cls[lm];
        #pragma unroll
        for (int r = 0; r < 4; ++r) {
            const int m = 4 * q + r;
            float acc = bo;
            #pragma unroll
            for (int j = 0; j < 10; ++j) acc += hfin[m * 12 + j] * wc[j];
            out[(size_t)(sbase + m) * 10 + lm] = acc;
        }
    }
}

extern "C" void kernel_launch(void* const* d_in, const int* in_sizes, int n_in,
                              void* d_out, int out_size, void* d_ws, size_t ws_size,
                              hipStream_t stream) {
    const float* x     = (const float*)d_in[0];
    const float* w_ih0 = (const float*)d_in[1];
    const float* w_hh0 = (const float*)d_in[2];
    const float* b_ih0 = (const float*)d_in[3];
    const float* b_hh0 = (const float*)d_in[4];
    const float* w_ih1 = (const float*)d_in[5];
    const float* w_hh1 = (const float*)d_in[6];
    const float* b_ih1 = (const float*)d_in[7];
    const float* b_hh1 = (const float*)d_in[8];
    const float* w_cls = (const float*)d_in[9];
    const float* b_cls = (const float*)d_in[10];
    float* out = (float*)d_out;

    const int B = in_sizes[0] / (TSTEPS * DDIM);   // 32768
    const int grid = B / 16;                       // 2048 blocks of 1 wave

    hipLaunchKernelGGL(lstm2_mfma_kernel, dim3(grid), dim3(64), 0, stream,
                       x, w_ih0, w_hh0, b_ih0, b_hh0,
                       w_ih1, w_hh1, b_ih1, b_hh1,
                       w_cls, b_cls, out);
}